// Round 1
// baseline (336.098 us; speedup 1.0000x reference)
//
#include <hip/hip_runtime.h>
#include <math.h>

#define NB     65536
#define NSP    26
#define NDN    13
#define EMBD   5
#define VOCAB  100000
#define NE     4
#define DIN    143   // 13 + 26*5
#define H1     128
#define H2     64
#define ROWS   32
#define THREADS 256

__global__ __launch_bounds__(THREADS)
void mmoe_fused(const int*   __restrict__ sparse,  // [B,26]
                const float* __restrict__ dense,   // [B,13]
                const float* __restrict__ emb,     // [26,100000,5]
                const float* __restrict__ W1,      // [4,143,128]
                const float* __restrict__ b1,      // [4,128]
                const float* __restrict__ W2,      // [4,128,64]
                const float* __restrict__ b2,      // [4,64]
                const float* __restrict__ gfW,     // [143,4]
                const float* __restrict__ gfb,     // [4]
                const float* __restrict__ glW,     // [143,4]
                const float* __restrict__ glb,     // [4]
                const float* __restrict__ fW,      // [64,1]
                const float* __restrict__ fb,      // [1]
                const float* __restrict__ lW,      // [64,1]
                const float* __restrict__ lb,      // [1]
                float* __restrict__ out)           // [2*B] : finish | like
{
    __shared__ float xs[ROWS][DIN + 1];   // +1 pad
    __shared__ float hs[ROWS][H1];
    __shared__ float glog[ROWS][2][NE];
    __shared__ float gate_f[ROWS][NE];
    __shared__ float gate_l[ROWS][NE];

    const int tid  = threadIdx.x;
    const int row0 = blockIdx.x * ROWS;

    // ---- Phase 0: gather x = [dense(13) | emb(26*5)] into LDS ----
    for (int k = tid; k < ROWS * DIN; k += THREADS) {
        int r = k / DIN;
        int d = k - r * DIN;
        int gr = row0 + r;
        float v;
        if (d < NDN) {
            v = dense[gr * NDN + d];
        } else {
            int q = d - NDN;
            int f = q / EMBD;
            int c = q - f * EMBD;
            int idx = sparse[gr * NSP + f];
            v = emb[(f * VOCAB + idx) * EMBD + c];
        }
        xs[r][d] = v;
    }
    __syncthreads();

    // ---- Phase 1: gate logits. tid -> row=tid>>3, e=(tid>>1)&3, which=tid&1 ----
    {
        int r = tid >> 3;
        int e = (tid >> 1) & 3;
        int which = tid & 1;
        const float* gW = which ? glW : gfW;
        float acc = which ? glb[e] : gfb[e];
        for (int d = 0; d < DIN; ++d)
            acc = fmaf(xs[r][d], gW[d * NE + e], acc);
        glog[r][which][e] = acc;
    }
    __syncthreads();
    if (tid < ROWS * 2) {
        int r = tid >> 1, which = tid & 1;
        float m = glog[r][which][0];
        #pragma unroll
        for (int e = 1; e < NE; ++e) m = fmaxf(m, glog[r][which][e]);
        float ex[NE], s = 0.f;
        #pragma unroll
        for (int e = 0; e < NE; ++e) { ex[e] = expf(glog[r][which][e] - m); s += ex[e]; }
        float inv = 1.f / s;
        #pragma unroll
        for (int e = 0; e < NE; ++e) {
            float g = ex[e] * inv;
            if (which) gate_l[r][e] = g; else gate_f[r][e] = g;
        }
    }
    __syncthreads();

    // ---- Main expert loop. Microtile mapping (same for both GEMMs): ----
    // cg = tid&31, rg = tid>>5 (0..7). Stage A: rows rg*4+rr, cols cg*4+cc.
    // Stage B: rows rg*4+rr, cols cg*2+cc. Task accumulators live in regs.
    const int cg = tid & 31;
    const int rg = tid >> 5;

    float tf0[4], tf1[4], tl0[4], tl1[4];
    #pragma unroll
    for (int rr = 0; rr < 4; ++rr) { tf0[rr] = tf1[rr] = tl0[rr] = tl1[rr] = 0.f; }

    for (int e = 0; e < NE; ++e) {
        // Stage A: h = relu(x @ W1[e] + b1[e]) -> hs
        const float* W1e = W1 + e * DIN * H1;
        float acc[4][4];
        #pragma unroll
        for (int rr = 0; rr < 4; ++rr)
            acc[rr][0] = acc[rr][1] = acc[rr][2] = acc[rr][3] = 0.f;
        for (int d = 0; d < DIN; ++d) {
            const float4 w = *(const float4*)(W1e + d * H1 + cg * 4);
            #pragma unroll
            for (int rr = 0; rr < 4; ++rr) {
                float xv = xs[rg * 4 + rr][d];
                acc[rr][0] = fmaf(xv, w.x, acc[rr][0]);
                acc[rr][1] = fmaf(xv, w.y, acc[rr][1]);
                acc[rr][2] = fmaf(xv, w.z, acc[rr][2]);
                acc[rr][3] = fmaf(xv, w.w, acc[rr][3]);
            }
        }
        const float4 b1v = *(const float4*)(b1 + e * H1 + cg * 4);
        #pragma unroll
        for (int rr = 0; rr < 4; ++rr) {
            float4 hv;
            hv.x = fmaxf(acc[rr][0] + b1v.x, 0.f);
            hv.y = fmaxf(acc[rr][1] + b1v.y, 0.f);
            hv.z = fmaxf(acc[rr][2] + b1v.z, 0.f);
            hv.w = fmaxf(acc[rr][3] + b1v.w, 0.f);
            *(float4*)(&hs[rg * 4 + rr][cg * 4]) = hv;
        }
        __syncthreads();

        // Stage B: expert_out = relu(h @ W2[e] + b2[e]); fold into task accums
        const float* W2e = W2 + e * H1 * H2;
        float c0[4], c1[4];
        #pragma unroll
        for (int rr = 0; rr < 4; ++rr) { c0[rr] = c1[rr] = 0.f; }
        for (int d = 0; d < H1; ++d) {
            const float2 w = *(const float2*)(W2e + d * H2 + cg * 2);
            #pragma unroll
            for (int rr = 0; rr < 4; ++rr) {
                float hv = hs[rg * 4 + rr][d];
                c0[rr] = fmaf(hv, w.x, c0[rr]);
                c1[rr] = fmaf(hv, w.y, c1[rr]);
            }
        }
        const float2 b2v = *(const float2*)(b2 + e * H2 + cg * 2);
        #pragma unroll
        for (int rr = 0; rr < 4; ++rr) {
            int r = rg * 4 + rr;
            float eo0 = fmaxf(c0[rr] + b2v.x, 0.f);
            float eo1 = fmaxf(c1[rr] + b2v.y, 0.f);
            float gf = gate_f[r][e], gl = gate_l[r][e];
            tf0[rr] = fmaf(gf, eo0, tf0[rr]);
            tf1[rr] = fmaf(gf, eo1, tf1[rr]);
            tl0[rr] = fmaf(gl, eo0, tl0[rr]);
            tl1[rr] = fmaf(gl, eo1, tl1[rr]);
        }
        __syncthreads();  // hs reuse next expert
    }

    // ---- Heads: reduce over 64 cols (spread across 32-lane half-wave) ----
    const float fw0 = fW[cg * 2], fw1 = fW[cg * 2 + 1];
    const float lw0 = lW[cg * 2], lw1 = lW[cg * 2 + 1];
    const float fbv = fb[0], lbv = lb[0];
    #pragma unroll
    for (int rr = 0; rr < 4; ++rr) {
        float vf = tf0[rr] * fw0 + tf1[rr] * fw1;
        float vl = tl0[rr] * lw0 + tl1[rr] * lw1;
        #pragma unroll
        for (int m = 16; m >= 1; m >>= 1) {
            vf += __shfl_xor(vf, m);
            vl += __shfl_xor(vl, m);
        }
        if (cg == 0) {
            int r = row0 + rg * 4 + rr;
            out[r]      = 1.f / (1.f + expf(-(vf + fbv)));
            out[NB + r] = 1.f / (1.f + expf(-(vl + lbv)));
        }
    }
}

extern "C" void kernel_launch(void* const* d_in, const int* in_sizes, int n_in,
                              void* d_out, int out_size, void* d_ws, size_t ws_size,
                              hipStream_t stream) {
    dim3 grid(NB / ROWS), block(THREADS);
    mmoe_fused<<<grid, block, 0, stream>>>(
        (const int*)  d_in[0],   // sparse_inputs
        (const float*)d_in[1],   // dense_inputs
        (const float*)d_in[2],   // emb_tables
        (const float*)d_in[3],   // expert_W1
        (const float*)d_in[4],   // expert_b1
        (const float*)d_in[5],   // expert_W2
        (const float*)d_in[6],   // expert_b2
        (const float*)d_in[7],   // gate_finish_W
        (const float*)d_in[8],   // gate_finish_b
        (const float*)d_in[9],   // gate_like_W
        (const float*)d_in[10],  // gate_like_b
        (const float*)d_in[11],  // finish_W
        (const float*)d_in[12],  // finish_b
        (const float*)d_in[13],  // like_W
        (const float*)d_in[14],  // like_b
        (float*)d_out);
}

// Round 2
// 122.211 us; speedup vs baseline: 2.7501x; 2.7501x over previous
//
#include <hip/hip_runtime.h>
#include <math.h>

#define NB     65536
#define NSP    26
#define NDN    13
#define EMBD   5
#define VOCAB  100000
#define NE     4
#define DIN    143
#define KPAD   160   // DIN padded to multiple of 32
#define H1     128
#define H2     64

typedef __attribute__((ext_vector_type(8))) short bf16x8;
typedef __attribute__((ext_vector_type(4))) float f32x4;

__device__ __forceinline__ unsigned short f2bf(float f) {
    unsigned int u = __float_as_uint(f);
    u = (u + 0x7fff + ((u >> 16) & 1)) >> 16;   // RNE
    return (unsigned short)u;
}

// ---- preproc: build bf16 transposed weights in workspace ----
// w1t [4][128][160] (k-padded 0), w2t [4][64][128], gwc [16][160] (rows 0-3 gfW^T, 4-7 glW^T, 8-15 zero)
#define E1 (4*128*160)
#define E2 (4*64*128)
#define E3 (16*160)

__global__ __launch_bounds__(256)
void preproc(const float* __restrict__ W1, const float* __restrict__ W2,
             const float* __restrict__ gfW, const float* __restrict__ glW,
             unsigned short* __restrict__ w1t, unsigned short* __restrict__ w2t,
             unsigned short* __restrict__ gwc)
{
    int i = blockIdx.x * 256 + threadIdx.x;
    if (i < E1) {
        int k = i % KPAD;
        int n = (i / KPAD) & (H1 - 1);
        int e = i / (KPAD * H1);
        w1t[i] = (k < DIN) ? f2bf(W1[(e * DIN + k) * H1 + n]) : (unsigned short)0;
    } else if (i < E1 + E2) {
        int j = i - E1;
        int k = j & (H1 - 1);
        int o = (j >> 7) & (H2 - 1);
        int e = j >> 13;
        w2t[j] = f2bf(W2[(e * H1 + k) * H2 + o]);
    } else if (i < E1 + E2 + E3) {
        int j = i - (E1 + E2);
        int k = j % KPAD;
        int r = j / KPAD;
        float v = 0.f;
        if (k < DIN) {
            if (r < 4)      v = gfW[k * NE + r];
            else if (r < 8) v = glW[k * NE + (r - 4)];
        }
        gwc[j] = f2bf(v);
    }
}

// ---- main fused kernel: 64 rows/block, 4 waves, wave-private 16 rows, no barriers ----
__global__ __launch_bounds__(256)
void mmoe_mfma(const int*   __restrict__ sparse,
               const float* __restrict__ dense,
               const float* __restrict__ emb,
               const unsigned short* __restrict__ w1t,
               const float* __restrict__ b1,
               const unsigned short* __restrict__ w2t,
               const float* __restrict__ b2,
               const unsigned short* __restrict__ gwc,
               const float* __restrict__ gfb, const float* __restrict__ glb,
               const float* __restrict__ fW,  const float* __restrict__ fb,
               const float* __restrict__ lW,  const float* __restrict__ lb,
               float* __restrict__ out)
{
    __shared__ __align__(16) unsigned short xs[64][KPAD];   // bf16 x, stride 160 (320B: bank-balanced)
    __shared__ __align__(16) unsigned short hs[64][136];    // bf16 h, stride 136 (272B: bank-balanced)
    __shared__ __align__(16) float gts[64][8];              // gate_f[0..3] | gate_l[0..3]

    const int tid   = threadIdx.x;
    const int wid   = tid >> 6;
    const int lane  = tid & 63;
    const int b     = lane & 15;     // batch-within-wave / frag row index
    const int g     = lane >> 4;     // lane group 0..3
    const int rbase = wid * 16;
    const int grow0 = blockIdx.x * 64 + rbase;

    // ---- gather x (bf16) : dense | 26x5 emb | zero pad ----
    for (int t = lane; t < 16 * NDN; t += 64) {          // 208
        int r = t & 15, d = t >> 4;
        xs[rbase + r][d] = f2bf(dense[(grow0 + r) * NDN + d]);
    }
    for (int t = lane; t < 16 * (KPAD - DIN); t += 64) { // 272
        int r = t & 15, d = DIN + (t >> 4);
        xs[rbase + r][d] = 0;
    }
    for (int t = lane; t < 16 * NSP; t += 64) {          // 416
        int r = t & 15, f = t >> 4;
        int idx = sparse[(grow0 + r) * NSP + f];
        const float* ep = emb + (f * VOCAB + idx) * EMBD;
        int c0 = NDN + EMBD * f;
        #pragma unroll
        for (int c = 0; c < EMBD; ++c)
            xs[rbase + r][c0 + c] = f2bf(ep[c]);
    }
    // same-wave LDS dependency: compiler inserts lgkmcnt waits; no barrier needed.

    // ---- x fragments (B-operand: lane holds x[b][ks*32 + g*8 .. +7]) ----
    bf16x8 xf[5];
    #pragma unroll
    for (int s = 0; s < 5; ++s)
        xf[s] = *(const bf16x8*)&xs[rbase + b][32 * s + 8 * g];

    // ---- gates: one MFMA chain over combined [16][160] gate matrix ----
    f32x4 ga = {0.f, 0.f, 0.f, 0.f};
    #pragma unroll
    for (int s = 0; s < 5; ++s) {
        bf16x8 af = *(const bf16x8*)(gwc + b * KPAD + 32 * s + 8 * g);
        ga = __builtin_amdgcn_mfma_f32_16x16x32_bf16(af, xf[s], ga, 0, 0, 0);
    }
    if (g < 2) {   // g==0: finish-gate rows 0-3; g==1: like-gate rows 4-7
        const float4 bias = *(const float4*)(g ? glb : gfb);
        float l0 = ga[0] + bias.x, l1 = ga[1] + bias.y;
        float l2 = ga[2] + bias.z, l3 = ga[3] + bias.w;
        float m = fmaxf(fmaxf(l0, l1), fmaxf(l2, l3));
        float e0 = expf(l0 - m), e1 = expf(l1 - m), e2 = expf(l2 - m), e3 = expf(l3 - m);
        float inv = 1.f / (e0 + e1 + e2 + e3);
        float4 gv; gv.x = e0 * inv; gv.y = e1 * inv; gv.z = e2 * inv; gv.w = e3 * inv;
        *(float4*)&gts[rbase + b][g * 4] = gv;
    }

    // ---- expert loop ----
    float vf = 0.f, vl = 0.f;
    for (int e = 0; e < NE; ++e) {
        // Stage A: hT = W1T @ xT  -> lane holds h[batch=b][n = nt*16 + g*4 + reg]
        const unsigned short* w1e = w1t + e * (H1 * KPAD);
        #pragma unroll
        for (int nt = 0; nt < 8; ++nt) {
            f32x4 acc = {0.f, 0.f, 0.f, 0.f};
            #pragma unroll
            for (int s = 0; s < 5; ++s) {
                bf16x8 af = *(const bf16x8*)(w1e + (nt * 16 + b) * KPAD + 32 * s + 8 * g);
                acc = __builtin_amdgcn_mfma_f32_16x16x32_bf16(af, xf[s], acc, 0, 0, 0);
            }
            const float4 b1v = *(const float4*)(b1 + e * H1 + nt * 16 + 4 * g);
            unsigned lo = (unsigned)f2bf(fmaxf(acc[0] + b1v.x, 0.f)) |
                          ((unsigned)f2bf(fmaxf(acc[1] + b1v.y, 0.f)) << 16);
            unsigned hi = (unsigned)f2bf(fmaxf(acc[2] + b1v.z, 0.f)) |
                          ((unsigned)f2bf(fmaxf(acc[3] + b1v.w, 0.f)) << 16);
            uint2 hv; hv.x = lo; hv.y = hi;
            *(uint2*)&hs[rbase + b][nt * 16 + 4 * g] = hv;   // 4 consecutive neurons, 8B packed
        }

        // Stage B: outT = W2T @ hT ; h frags contiguous b128 reads
        bf16x8 hf[4];
        #pragma unroll
        for (int s = 0; s < 4; ++s)
            hf[s] = *(const bf16x8*)&hs[rbase + b][32 * s + 8 * g];

        float gf = gts[rbase + b][e];
        float gl = gts[rbase + b][4 + e];
        const unsigned short* w2e = w2t + e * (H2 * H1);
        #pragma unroll
        for (int ot = 0; ot < 4; ++ot) {
            f32x4 acc = {0.f, 0.f, 0.f, 0.f};
            #pragma unroll
            for (int s = 0; s < 4; ++s) {
                bf16x8 af = *(const bf16x8*)(w2e + (ot * 16 + b) * H1 + 32 * s + 8 * g);
                acc = __builtin_amdgcn_mfma_f32_16x16x32_bf16(af, hf[s], acc, 0, 0, 0);
            }
            const float4 b2v = *(const float4*)(b2 + e * H2 + ot * 16 + 4 * g);
            const float4 fwv = *(const float4*)(fW + ot * 16 + 4 * g);
            const float4 lwv = *(const float4*)(lW + ot * 16 + 4 * g);
            float o0 = fmaxf(acc[0] + b2v.x, 0.f);
            float o1 = fmaxf(acc[1] + b2v.y, 0.f);
            float o2 = fmaxf(acc[2] + b2v.z, 0.f);
            float o3 = fmaxf(acc[3] + b2v.w, 0.f);
            vf += gf * (o0 * fwv.x + o1 * fwv.y + o2 * fwv.z + o3 * fwv.w);
            vl += gl * (o0 * lwv.x + o1 * lwv.y + o2 * lwv.z + o3 * lwv.w);
        }
    }

    // ---- heads: reduce partials across the 4 lane groups, sigmoid, store ----
    vf += __shfl_xor(vf, 16); vf += __shfl_xor(vf, 32);
    vl += __shfl_xor(vl, 16); vl += __shfl_xor(vl, 32);
    if (g == 0) {
        int r = grow0 + b;
        out[r]      = 1.f / (1.f + expf(-(vf + fb[0])));
        out[NB + r] = 1.f / (1.f + expf(-(vl + lb[0])));
    }
}

extern "C" void kernel_launch(void* const* d_in, const int* in_sizes, int n_in,
                              void* d_out, int out_size, void* d_ws, size_t ws_size,
                              hipStream_t stream) {
    const int*   sparse = (const int*)  d_in[0];
    const float* dense  = (const float*)d_in[1];
    const float* emb    = (const float*)d_in[2];
    const float* W1     = (const float*)d_in[3];
    const float* b1     = (const float*)d_in[4];
    const float* W2     = (const float*)d_in[5];
    const float* b2     = (const float*)d_in[6];
    const float* gfW    = (const float*)d_in[7];
    const float* gfb    = (const float*)d_in[8];
    const float* glW    = (const float*)d_in[9];
    const float* glb    = (const float*)d_in[10];
    const float* fW     = (const float*)d_in[11];
    const float* fb     = (const float*)d_in[12];
    const float* lW     = (const float*)d_in[13];
    const float* lb     = (const float*)d_in[14];

    unsigned short* w1t = (unsigned short*)d_ws;                       // 163840 B
    unsigned short* w2t = (unsigned short*)((char*)d_ws + 163840);     //  65536 B
    unsigned short* gwc = (unsigned short*)((char*)d_ws + 229376);     //   5120 B

    int tot = E1 + E2 + E3;
    preproc<<<(tot + 255) / 256, 256, 0, stream>>>(W1, W2, gfW, glW, w1t, w2t, gwc);
    mmoe_mfma<<<NB / 64, 256, 0, stream>>>(sparse, dense, emb,
                                           w1t, b1, w2t, b2, gwc,
                                           gfb, glb, fW, fb, lW, lb,
                                           (float*)d_out);
}

// Round 3
// 106.652 us; speedup vs baseline: 3.1513x; 1.1459x over previous
//
#include <hip/hip_runtime.h>
#include <math.h>

#define NB     65536
#define NSP    26
#define NDN    13
#define EMBD   5
#define VOCAB  100000
#define NE     4
#define DIN    143
#define KPAD   160
#define H1     128
#define H2     64

typedef __attribute__((ext_vector_type(8))) short bf16x8;
typedef __attribute__((ext_vector_type(4))) float f32x4;

__device__ __forceinline__ unsigned short f2bf(float f) {
    unsigned int u = __float_as_uint(f);
    u = (u + 0x7fff + ((u >> 16) & 1)) >> 16;   // RNE
    return (unsigned short)u;
}

#define E1 (4*128*160)
#define E2 (4*64*128)
#define E3 (16*160)
#define G_EMB (NB*NSP)
#define G_DNP (NB*30)

// ============================================================================
// FAST PATH
// ============================================================================

// one mega elementwise kernel: embedding gather -> xg (bf16 [B][160]),
// dense+pad -> xg, plus bf16 transposed weight builds. All waves gather
// simultaneously -> maximal outstanding misses.
__global__ __launch_bounds__(256)
void gather_prep(const int*   __restrict__ sparse,
                 const float* __restrict__ dense,
                 const float* __restrict__ emb,
                 const float* __restrict__ W1,  const float* __restrict__ W2,
                 const float* __restrict__ gfW, const float* __restrict__ glW,
                 unsigned short* __restrict__ w1t, unsigned short* __restrict__ w2t,
                 unsigned short* __restrict__ gwc, unsigned short* __restrict__ xg)
{
    int i = blockIdx.x * 256 + threadIdx.x;
    if (i < G_EMB) {
        // one thread per (row, feature): 1 idx load + 5 table loads
        int r = i / NSP, f = i - r * NSP;
        int idx = sparse[i];
        const float* ep = emb + (f * VOCAB + idx) * EMBD;
        unsigned short* xp = xg + r * KPAD + NDN + f * EMBD;
        #pragma unroll
        for (int c = 0; c < EMBD; ++c) xp[c] = f2bf(ep[c]);
        return;
    }
    i -= G_EMB;
    if (i < G_DNP) {
        int r = i / 30, c = i - r * 30;
        if (c < NDN) xg[r * KPAD + c] = f2bf(dense[r * NDN + c]);
        else         xg[r * KPAD + 130 + c] = 0;   // cols 143..159
        return;
    }
    i -= G_DNP;
    if (i < E1) {
        int k = i % KPAD;
        int n = (i / KPAD) & (H1 - 1);
        int e = i / (KPAD * H1);
        w1t[i] = (k < DIN) ? f2bf(W1[(e * DIN + k) * H1 + n]) : (unsigned short)0;
        return;
    }
    i -= E1;
    if (i < E2) {
        int k = i & (H1 - 1);
        int o = (i >> 7) & (H2 - 1);
        int e = i >> 13;
        w2t[i] = f2bf(W2[(e * H1 + k) * H2 + o]);
        return;
    }
    i -= E2;
    if (i < E3) {
        int k = i % KPAD;
        int r = i / KPAD;
        float v = 0.f;
        if (k < DIN) {
            if (r < 4)      v = gfW[k * NE + r];
            else if (r < 8) v = glW[k * NE + (r - 4)];
        }
        gwc[i] = f2bf(v);
    }
}

// compute kernel: 4 waves * 32 rows = 128 rows/block, wave-private, no barriers.
// Each weight fragment feeds 2 row-tiles (halves L2 weight traffic, doubles ILP).
__global__ __launch_bounds__(256)
void mmoe2(const unsigned short* __restrict__ xg,
           const unsigned short* __restrict__ w1t, const float* __restrict__ b1,
           const unsigned short* __restrict__ w2t, const float* __restrict__ b2,
           const unsigned short* __restrict__ gwc,
           const float* __restrict__ gfb, const float* __restrict__ glb,
           const float* __restrict__ fW,  const float* __restrict__ fb,
           const float* __restrict__ lW,  const float* __restrict__ lb,
           float* __restrict__ out)
{
    __shared__ __align__(16) unsigned short hs[128][136];
    __shared__ __align__(16) float gts[128][8];

    const int tid  = threadIdx.x;
    const int wid  = tid >> 6;
    const int lane = tid & 63;
    const int b    = lane & 15;
    const int g    = lane >> 4;
    const int wrow = wid * 32;                    // wave base inside block
    const int grow = blockIdx.x * 128 + wrow;     // global base

    // ---- x fragments straight from global (coalesced 64B-per-4-lane lines) ----
    bf16x8 xf[2][5];
    #pragma unroll
    for (int rt = 0; rt < 2; ++rt)
        #pragma unroll
        for (int s = 0; s < 5; ++s)
            xf[rt][s] = *(const bf16x8*)(xg + (grow + rt * 16 + b) * KPAD + 32 * s + 8 * g);

    // ---- gates: shared A-fragment across both row-tiles ----
    f32x4 ga[2];
    ga[0] = (f32x4){0.f, 0.f, 0.f, 0.f};
    ga[1] = (f32x4){0.f, 0.f, 0.f, 0.f};
    #pragma unroll
    for (int s = 0; s < 5; ++s) {
        bf16x8 af = *(const bf16x8*)(gwc + b * KPAD + 32 * s + 8 * g);
        ga[0] = __builtin_amdgcn_mfma_f32_16x16x32_bf16(af, xf[0][s], ga[0], 0, 0, 0);
        ga[1] = __builtin_amdgcn_mfma_f32_16x16x32_bf16(af, xf[1][s], ga[1], 0, 0, 0);
    }
    if (g < 2) {
        const float4 bias = *(const float4*)(g ? glb : gfb);
        #pragma unroll
        for (int rt = 0; rt < 2; ++rt) {
            float l0 = ga[rt][0] + bias.x, l1 = ga[rt][1] + bias.y;
            float l2 = ga[rt][2] + bias.z, l3 = ga[rt][3] + bias.w;
            float m = fmaxf(fmaxf(l0, l1), fmaxf(l2, l3));
            float e0 = expf(l0 - m), e1 = expf(l1 - m), e2 = expf(l2 - m), e3 = expf(l3 - m);
            float inv = 1.f / (e0 + e1 + e2 + e3);
            float4 gv; gv.x = e0 * inv; gv.y = e1 * inv; gv.z = e2 * inv; gv.w = e3 * inv;
            *(float4*)&gts[wrow + rt * 16 + b][g * 4] = gv;
        }
    }

    // ---- expert loop ----
    float vf0 = 0.f, vl0 = 0.f, vf1 = 0.f, vl1 = 0.f;
    for (int e = 0; e < NE; ++e) {
        const unsigned short* w1e = w1t + e * (H1 * KPAD);
        #pragma unroll
        for (int nt = 0; nt < 8; ++nt) {
            f32x4 a0 = {0.f, 0.f, 0.f, 0.f};
            f32x4 a1 = {0.f, 0.f, 0.f, 0.f};
            #pragma unroll
            for (int s = 0; s < 5; ++s) {
                bf16x8 af = *(const bf16x8*)(w1e + (nt * 16 + b) * KPAD + 32 * s + 8 * g);
                a0 = __builtin_amdgcn_mfma_f32_16x16x32_bf16(af, xf[0][s], a0, 0, 0, 0);
                a1 = __builtin_amdgcn_mfma_f32_16x16x32_bf16(af, xf[1][s], a1, 0, 0, 0);
            }
            const float4 b1v = *(const float4*)(b1 + e * H1 + nt * 16 + 4 * g);
            {
                unsigned lo = (unsigned)f2bf(fmaxf(a0[0] + b1v.x, 0.f)) |
                              ((unsigned)f2bf(fmaxf(a0[1] + b1v.y, 0.f)) << 16);
                unsigned hi = (unsigned)f2bf(fmaxf(a0[2] + b1v.z, 0.f)) |
                              ((unsigned)f2bf(fmaxf(a0[3] + b1v.w, 0.f)) << 16);
                uint2 hv; hv.x = lo; hv.y = hi;
                *(uint2*)&hs[wrow + b][nt * 16 + 4 * g] = hv;
            }
            {
                unsigned lo = (unsigned)f2bf(fmaxf(a1[0] + b1v.x, 0.f)) |
                              ((unsigned)f2bf(fmaxf(a1[1] + b1v.y, 0.f)) << 16);
                unsigned hi = (unsigned)f2bf(fmaxf(a1[2] + b1v.z, 0.f)) |
                              ((unsigned)f2bf(fmaxf(a1[3] + b1v.w, 0.f)) << 16);
                uint2 hv; hv.x = lo; hv.y = hi;
                *(uint2*)&hs[wrow + 16 + b][nt * 16 + 4 * g] = hv;
            }
        }

        bf16x8 hf0[4], hf1[4];
        #pragma unroll
        for (int s = 0; s < 4; ++s) {
            hf0[s] = *(const bf16x8*)&hs[wrow + b][32 * s + 8 * g];
            hf1[s] = *(const bf16x8*)&hs[wrow + 16 + b][32 * s + 8 * g];
        }
        float gf0 = gts[wrow + b][e],      gl0 = gts[wrow + b][4 + e];
        float gf1 = gts[wrow + 16 + b][e], gl1 = gts[wrow + 16 + b][4 + e];

        const unsigned short* w2e = w2t + e * (H2 * H1);
        #pragma unroll
        for (int ot = 0; ot < 4; ++ot) {
            f32x4 c0 = {0.f, 0.f, 0.f, 0.f};
            f32x4 c1 = {0.f, 0.f, 0.f, 0.f};
            #pragma unroll
            for (int s = 0; s < 4; ++s) {
                bf16x8 af = *(const bf16x8*)(w2e + (ot * 16 + b) * H1 + 32 * s + 8 * g);
                c0 = __builtin_amdgcn_mfma_f32_16x16x32_bf16(af, hf0[s], c0, 0, 0, 0);
                c1 = __builtin_amdgcn_mfma_f32_16x16x32_bf16(af, hf1[s], c1, 0, 0, 0);
            }
            const float4 b2v = *(const float4*)(b2 + e * H2 + ot * 16 + 4 * g);
            const float4 fwv = *(const float4*)(fW + ot * 16 + 4 * g);
            const float4 lwv = *(const float4*)(lW + ot * 16 + 4 * g);
            float o0 = fmaxf(c0[0] + b2v.x, 0.f), o1 = fmaxf(c0[1] + b2v.y, 0.f);
            float o2 = fmaxf(c0[2] + b2v.z, 0.f), o3 = fmaxf(c0[3] + b2v.w, 0.f);
            vf0 += gf0 * (o0 * fwv.x + o1 * fwv.y + o2 * fwv.z + o3 * fwv.w);
            vl0 += gl0 * (o0 * lwv.x + o1 * lwv.y + o2 * lwv.z + o3 * lwv.w);
            float p0 = fmaxf(c1[0] + b2v.x, 0.f), p1 = fmaxf(c1[1] + b2v.y, 0.f);
            float p2 = fmaxf(c1[2] + b2v.z, 0.f), p3 = fmaxf(c1[3] + b2v.w, 0.f);
            vf1 += gf1 * (p0 * fwv.x + p1 * fwv.y + p2 * fwv.z + p3 * fwv.w);
            vl1 += gl1 * (p0 * lwv.x + p1 * lwv.y + p2 * lwv.z + p3 * lwv.w);
        }
    }

    // ---- heads ----
    vf0 += __shfl_xor(vf0, 16); vf0 += __shfl_xor(vf0, 32);
    vl0 += __shfl_xor(vl0, 16); vl0 += __shfl_xor(vl0, 32);
    vf1 += __shfl_xor(vf1, 16); vf1 += __shfl_xor(vf1, 32);
    vl1 += __shfl_xor(vl1, 16); vl1 += __shfl_xor(vl1, 32);
    if (g == 0) {
        int r0 = blockIdx.x * 128 + wrow + b;
        out[r0]           = 1.f / (1.f + expf(-(vf0 + fb[0])));
        out[NB + r0]      = 1.f / (1.f + expf(-(vl0 + lb[0])));
        out[r0 + 16]      = 1.f / (1.f + expf(-(vf1 + fb[0])));
        out[NB + r0 + 16] = 1.f / (1.f + expf(-(vl1 + lb[0])));
    }
}

// ============================================================================
// FALLBACK PATH (round-2 kernels, used only if ws_size < 21.2 MB)
// ============================================================================

__global__ __launch_bounds__(256)
void preproc(const float* __restrict__ W1, const float* __restrict__ W2,
             const float* __restrict__ gfW, const float* __restrict__ glW,
             unsigned short* __restrict__ w1t, unsigned short* __restrict__ w2t,
             unsigned short* __restrict__ gwc)
{
    int i = blockIdx.x * 256 + threadIdx.x;
    if (i < E1) {
        int k = i % KPAD;
        int n = (i / KPAD) & (H1 - 1);
        int e = i / (KPAD * H1);
        w1t[i] = (k < DIN) ? f2bf(W1[(e * DIN + k) * H1 + n]) : (unsigned short)0;
    } else if (i < E1 + E2) {
        int j = i - E1;
        int k = j & (H1 - 1);
        int o = (j >> 7) & (H2 - 1);
        int e = j >> 13;
        w2t[j] = f2bf(W2[(e * H1 + k) * H2 + o]);
    } else if (i < E1 + E2 + E3) {
        int j = i - (E1 + E2);
        int k = j % KPAD;
        int r = j / KPAD;
        float v = 0.f;
        if (k < DIN) {
            if (r < 4)      v = gfW[k * NE + r];
            else if (r < 8) v = glW[k * NE + (r - 4)];
        }
        gwc[j] = f2bf(v);
    }
}

__global__ __launch_bounds__(256)
void mmoe_mfma(const int*   __restrict__ sparse,
               const float* __restrict__ dense,
               const float* __restrict__ emb,
               const unsigned short* __restrict__ w1t,
               const float* __restrict__ b1,
               const unsigned short* __restrict__ w2t,
               const float* __restrict__ b2,
               const unsigned short* __restrict__ gwc,
               const float* __restrict__ gfb, const float* __restrict__ glb,
               const float* __restrict__ fW,  const float* __restrict__ fb,
               const float* __restrict__ lW,  const float* __restrict__ lb,
               float* __restrict__ out)
{
    __shared__ __align__(16) unsigned short xs[64][KPAD];
    __shared__ __align__(16) unsigned short hs[64][136];
    __shared__ __align__(16) float gts[64][8];

    const int tid   = threadIdx.x;
    const int wid   = tid >> 6;
    const int lane  = tid & 63;
    const int b     = lane & 15;
    const int g     = lane >> 4;
    const int rbase = wid * 16;
    const int grow0 = blockIdx.x * 64 + rbase;

    for (int t = lane; t < 16 * NDN; t += 64) {
        int r = t & 15, d = t >> 4;
        xs[rbase + r][d] = f2bf(dense[(grow0 + r) * NDN + d]);
    }
    for (int t = lane; t < 16 * (KPAD - DIN); t += 64) {
        int r = t & 15, d = DIN + (t >> 4);
        xs[rbase + r][d] = 0;
    }
    for (int t = lane; t < 16 * NSP; t += 64) {
        int r = t & 15, f = t >> 4;
        int idx = sparse[(grow0 + r) * NSP + f];
        const float* ep = emb + (f * VOCAB + idx) * EMBD;
        int c0 = NDN + EMBD * f;
        #pragma unroll
        for (int c = 0; c < EMBD; ++c)
            xs[rbase + r][c0 + c] = f2bf(ep[c]);
    }

    bf16x8 xf[5];
    #pragma unroll
    for (int s = 0; s < 5; ++s)
        xf[s] = *(const bf16x8*)&xs[rbase + b][32 * s + 8 * g];

    f32x4 ga = {0.f, 0.f, 0.f, 0.f};
    #pragma unroll
    for (int s = 0; s < 5; ++s) {
        bf16x8 af = *(const bf16x8*)(gwc + b * KPAD + 32 * s + 8 * g);
        ga = __builtin_amdgcn_mfma_f32_16x16x32_bf16(af, xf[s], ga, 0, 0, 0);
    }
    if (g < 2) {
        const float4 bias = *(const float4*)(g ? glb : gfb);
        float l0 = ga[0] + bias.x, l1 = ga[1] + bias.y;
        float l2 = ga[2] + bias.z, l3 = ga[3] + bias.w;
        float m = fmaxf(fmaxf(l0, l1), fmaxf(l2, l3));
        float e0 = expf(l0 - m), e1 = expf(l1 - m), e2 = expf(l2 - m), e3 = expf(l3 - m);
        float inv = 1.f / (e0 + e1 + e2 + e3);
        float4 gv; gv.x = e0 * inv; gv.y = e1 * inv; gv.z = e2 * inv; gv.w = e3 * inv;
        *(float4*)&gts[rbase + b][g * 4] = gv;
    }

    float vf = 0.f, vl = 0.f;
    for (int e = 0; e < NE; ++e) {
        const unsigned short* w1e = w1t + e * (H1 * KPAD);
        #pragma unroll
        for (int nt = 0; nt < 8; ++nt) {
            f32x4 acc = {0.f, 0.f, 0.f, 0.f};
            #pragma unroll
            for (int s = 0; s < 5; ++s) {
                bf16x8 af = *(const bf16x8*)(w1e + (nt * 16 + b) * KPAD + 32 * s + 8 * g);
                acc = __builtin_amdgcn_mfma_f32_16x16x32_bf16(af, xf[s], acc, 0, 0, 0);
            }
            const float4 b1v = *(const float4*)(b1 + e * H1 + nt * 16 + 4 * g);
            unsigned lo = (unsigned)f2bf(fmaxf(acc[0] + b1v.x, 0.f)) |
                          ((unsigned)f2bf(fmaxf(acc[1] + b1v.y, 0.f)) << 16);
            unsigned hi = (unsigned)f2bf(fmaxf(acc[2] + b1v.z, 0.f)) |
                          ((unsigned)f2bf(fmaxf(acc[3] + b1v.w, 0.f)) << 16);
            uint2 hv; hv.x = lo; hv.y = hi;
            *(uint2*)&hs[rbase + b][nt * 16 + 4 * g] = hv;
        }

        bf16x8 hf[4];
        #pragma unroll
        for (int s = 0; s < 4; ++s)
            hf[s] = *(const bf16x8*)&hs[rbase + b][32 * s + 8 * g];

        float gf = gts[rbase + b][e];
        float gl = gts[rbase + b][4 + e];
        const unsigned short* w2e = w2t + e * (H2 * H1);
        #pragma unroll
        for (int ot = 0; ot < 4; ++ot) {
            f32x4 acc = {0.f, 0.f, 0.f, 0.f};
            #pragma unroll
            for (int s = 0; s < 4; ++s) {
                bf16x8 af = *(const bf16x8*)(w2e + (ot * 16 + b) * H1 + 32 * s + 8 * g);
                acc = __builtin_amdgcn_mfma_f32_16x16x32_bf16(af, hf[s], acc, 0, 0, 0);
            }
            const float4 b2v = *(const float4*)(b2 + e * H2 + ot * 16 + 4 * g);
            const float4 fwv = *(const float4*)(fW + ot * 16 + 4 * g);
            const float4 lwv = *(const float4*)(lW + ot * 16 + 4 * g);
            float o0 = fmaxf(acc[0] + b2v.x, 0.f);
            float o1 = fmaxf(acc[1] + b2v.y, 0.f);
            float o2 = fmaxf(acc[2] + b2v.z, 0.f);
            float o3 = fmaxf(acc[3] + b2v.w, 0.f);
            vf += gf * (o0 * fwv.x + o1 * fwv.y + o2 * fwv.z + o3 * fwv.w);
            vl += gl * (o0 * lwv.x + o1 * lwv.y + o2 * lwv.z + o3 * lwv.w);
        }
    }

    vf += __shfl_xor(vf, 16); vf += __shfl_xor(vf, 32);
    vl += __shfl_xor(vl, 16); vl += __shfl_xor(vl, 32);
    if (g == 0) {
        int r = grow0 + b;
        out[r]      = 1.f / (1.f + expf(-(vf + fb[0])));
        out[NB + r] = 1.f / (1.f + expf(-(vl + lb[0])));
    }
}

// ============================================================================

extern "C" void kernel_launch(void* const* d_in, const int* in_sizes, int n_in,
                              void* d_out, int out_size, void* d_ws, size_t ws_size,
                              hipStream_t stream) {
    const int*   sparse = (const int*)  d_in[0];
    const float* dense  = (const float*)d_in[1];
    const float* emb    = (const float*)d_in[2];
    const float* W1     = (const float*)d_in[3];
    const float* b1     = (const float*)d_in[4];
    const float* W2     = (const float*)d_in[5];
    const float* b2     = (const float*)d_in[6];
    const float* gfW    = (const float*)d_in[7];
    const float* gfb    = (const float*)d_in[8];
    const float* glW    = (const float*)d_in[9];
    const float* glb    = (const float*)d_in[10];
    const float* fW     = (const float*)d_in[11];
    const float* fb     = (const float*)d_in[12];
    const float* lW     = (const float*)d_in[13];
    const float* lb     = (const float*)d_in[14];

    const size_t XG_BYTES = (size_t)NB * KPAD * 2;            // 20,971,520
    const size_t NEED = XG_BYTES + 163840 + 65536 + 5120;     // ~21.2 MB

    if (ws_size >= NEED) {
        unsigned short* xg  = (unsigned short*)d_ws;
        unsigned short* w1t = (unsigned short*)((char*)d_ws + XG_BYTES);
        unsigned short* w2t = (unsigned short*)((char*)d_ws + XG_BYTES + 163840);
        unsigned short* gwc = (unsigned short*)((char*)d_ws + XG_BYTES + 163840 + 65536);

        int tot = G_EMB + G_DNP + E1 + E2 + E3;
        gather_prep<<<(tot + 255) / 256, 256, 0, stream>>>(
            sparse, dense, emb, W1, W2, gfW, glW, w1t, w2t, gwc, xg);
        mmoe2<<<NB / 128, 256, 0, stream>>>(xg, w1t, b1, w2t, b2, gwc,
                                            gfb, glb, fW, fb, lW, lb,
                                            (float*)d_out);
    } else {
        unsigned short* w1t = (unsigned short*)d_ws;
        unsigned short* w2t = (unsigned short*)((char*)d_ws + 163840);
        unsigned short* gwc = (unsigned short*)((char*)d_ws + 229376);

        int tot = E1 + E2 + E3;
        preproc<<<(tot + 255) / 256, 256, 0, stream>>>(W1, W2, gfW, glW, w1t, w2t, gwc);
        mmoe_mfma<<<NB / 64, 256, 0, stream>>>(sparse, dense, emb,
                                               w1t, b1, w2t, b2, gwc,
                                               gfb, glb, fW, fb, lW, lb,
                                               (float*)d_out);
    }
}